// Round 6
// baseline (725.026 us; speedup 1.0000x reference)
//
#include <hip/hip_runtime.h>

#define N_ROWS 65536
#define DIM    512
#define K_CENT 4096
#define TILE_M 128               // rows per block = 4 waves x 32 private rows
#define TILE_N 64                // centers per tile
#define NCT    (K_CENT / TILE_N) // 64 tiles
#define KSTEPS 8                 // DIM / 64
#define THREADS 256
#define WCAP   1024              // per-wave candidate pool entries
#define WTRIG  512
#define MARGIN 22.0f
#define SCALE1 0x7F7F7F7F        // e8m0 scale = 2^0 in every byte

typedef float  floatx4  __attribute__((ext_vector_type(4)));
typedef float  floatx16 __attribute__((ext_vector_type(16)));
typedef int    intx4    __attribute__((ext_vector_type(4)));
typedef int    intx8    __attribute__((ext_vector_type(8)));

// order-preserving float<->uint map
__device__ __forceinline__ unsigned mapF(float f) {
  unsigned u = __float_as_uint(f);
  return (u & 0x80000000u) ? ~u : (u | 0x80000000u);
}
__device__ __forceinline__ float unmapF(unsigned m) {
  unsigned u = (m & 0x80000000u) ? (m ^ 0x80000000u) : ~m;
  return __uint_as_float(u);
}

// pack 4 floats -> 4 OCP e4m3 bytes
__device__ __forceinline__ int pk4(float a, float b, float c, float d) {
  int r = __builtin_amdgcn_cvt_pk_fp8_f32(a, b, 0, false);
  r = __builtin_amdgcn_cvt_pk_fp8_f32(c, d, r, true);
  return r;
}

// intra-wave LDS ordering fence (no barrier): drain lgkm, pin schedule
#define WAVE_LDS_FENCE() do { asm volatile("s_waitcnt lgkmcnt(0)" ::: "memory"); \
                              __builtin_amdgcn_sched_barrier(0); } while (0)

// Centers only: fp32 -> fp8 (16 elems/thread) + EXACT fp32 csq per row.
__global__ void prep_convert(const float* __restrict__ c,
                             unsigned char* __restrict__ cq, float* __restrict__ csqg) {
  size_t i = ((size_t)blockIdx.x * blockDim.x + threadIdx.x) * 16;
  if (i >= (size_t)K_CENT * DIM) return;
  floatx4 a0 = *(const floatx4*)(c + i);
  floatx4 a1 = *(const floatx4*)(c + i + 4);
  floatx4 a2 = *(const floatx4*)(c + i + 8);
  floatx4 a3 = *(const floatx4*)(c + i + 12);
  intx4 q = { pk4(a0[0],a0[1],a0[2],a0[3]), pk4(a1[0],a1[1],a1[2],a1[3]),
              pk4(a2[0],a2[1],a2[2],a2[3]), pk4(a3[0],a3[1],a3[2],a3[3]) };
  *(intx4*)(cq + i) = q;
  float s = 0.f;
#pragma unroll
  for (int e = 0; e < 4; ++e)
    s += a0[e]*a0[e] + a1[e]*a1[e] + a2[e]*a2[e] + a3[e]*a3[e];
#pragma unroll
  for (int o = 1; o < 32; o <<= 1) s += __shfl_xor(s, o, 64);
  if ((threadIdx.x & 31) == 0) csqg[i >> 9] = s;
}

// load one K-pair (2 steps of K=64) of center fragments into 8 intx4 regs.
// Per lane: A-operand row = ctB-relative l31 (p0) / l31+32 (p1), bytes
// [half*32, half*32+32) of each 64B k-chunk -> two dwordx4 at +0,+16.
// kb is compile-time (0,2,4,6): all offsets fold into load immediates.
#define LOADP(buf, p0, p1, kb) do {                                   \
  buf[0] = *(const intx4*)((p0) + (kb) * 64);                         \
  buf[1] = *(const intx4*)((p0) + (kb) * 64 + 16);                    \
  buf[2] = *(const intx4*)((p1) + (kb) * 64);                         \
  buf[3] = *(const intx4*)((p1) + (kb) * 64 + 16);                    \
  buf[4] = *(const intx4*)((p0) + (kb) * 64 + 64);                    \
  buf[5] = *(const intx4*)((p0) + (kb) * 64 + 80);                    \
  buf[6] = *(const intx4*)((p1) + (kb) * 64 + 64);                    \
  buf[7] = *(const intx4*)((p1) + (kb) * 64 + 80);                    \
} while (0)

// consume one K-pair: 4 MFMAs (2 center groups x 2 k-steps)
#define COMP(buf, kb) do {                                            \
  intx8 b0a = (intx8){buf[0][0],buf[0][1],buf[0][2],buf[0][3],        \
                      buf[1][0],buf[1][1],buf[1][2],buf[1][3]};       \
  intx8 b1a = (intx8){buf[2][0],buf[2][1],buf[2][2],buf[2][3],        \
                      buf[3][0],buf[3][1],buf[3][2],buf[3][3]};       \
  acc0 = __builtin_amdgcn_mfma_scale_f32_32x32x64_f8f6f4(             \
      b0a, xf[(kb)], acc0, 0, 0, 0, SCALE1, 0, SCALE1);               \
  acc1 = __builtin_amdgcn_mfma_scale_f32_32x32x64_f8f6f4(             \
      b1a, xf[(kb)], acc1, 0, 0, 0, SCALE1, 0, SCALE1);               \
  intx8 b0b = (intx8){buf[4][0],buf[4][1],buf[4][2],buf[4][3],        \
                      buf[5][0],buf[5][1],buf[5][2],buf[5][3]};       \
  intx8 b1b = (intx8){buf[6][0],buf[6][1],buf[6][2],buf[6][3],        \
                      buf[7][0],buf[7][1],buf[7][2],buf[7][3]};       \
  acc0 = __builtin_amdgcn_mfma_scale_f32_32x32x64_f8f6f4(             \
      b0b, xf[(kb) + 1], acc0, 0, 0, 0, SCALE1, 0, SCALE1);           \
  acc1 = __builtin_amdgcn_mfma_scale_f32_32x32x64_f8f6f4(             \
      b1b, xf[(kb) + 1], acc1, 0, 0, 0, SCALE1, 0, SCALE1);           \
} while (0)

// R6: NO LDS STAGING. Theory: glds path measured ~7-11 B/cy/CU across R0/R1/
// R5/m97 (per-CU step time invariant ~2300cy for 16KB staged regardless of
// barrier structure / occupancy / prefetch depth) -> every prior round was
// glds-throughput-bound at MfmaUtil ~12%. Center fragments are per-lane
// CONTIGUOUS 32B -> load them DIRECTLY to registers (normal loads: ~56 B/cy
// /CU from L2; cq 2MB = L2-resident; 4 waves/block read same tile -> L1 hits).
// Skeleton = R5 (passed): wave-private rows (wave w owns rows w*32..+31),
// x in registers, wave-local sminU/pool/LOSSLESS compaction, fp64 refine.
// K-loop is PURE C (no inline asm): double-buffered K-pairs (bufA/bufB, 8
// intx4 each), compiler inserts vmcnt waits. 2 blocks/CU (grid 512, ~50KB
// LDS) -> 2 waves/SIMD latency hiding. VGPR est ~205 < 256 cap (256,2).
__global__ __launch_bounds__(THREADS, 2)
void kmeans_argmin_pipe(const float* __restrict__ x, const float* __restrict__ cent,
                        const unsigned char* __restrict__ cq,
                        const float* __restrict__ csqg, int* __restrict__ out) {
  __shared__ __align__(16) float csqL[K_CENT];  // 16 KB
  __shared__ unsigned sminU[TILE_M];            // 0.5 KB
  __shared__ unsigned long long best[TILE_M];   // 1 KB
  __shared__ unsigned poolK[4][WCAP];           // 16 KB
  __shared__ float    poolS[4][WCAP];           // 16 KB
  __shared__ int candCnt[4];

  const int t = threadIdx.x;
  const int lane = t & 63;
  const int wave = t >> 6;        // 0..3
  const int l31 = lane & 31;
  const int half = lane >> 5;
  const int rowBlock = blockIdx.x * TILE_M;
  const int srow = wave * 32 + l31;   // my x-row (C col = lane&31); wave-private

  if (t < TILE_M) { sminU[t] = 0xFFFFFFFFu; best[t] = ~0ull; }
  if (t < 4) candCnt[t] = 0;
#pragma unroll
  for (int i = 0; i < K_CENT / THREADS; ++i) csqL[t + i * THREADS] = csqg[t + i * THREADS];

  // ---- x -> fp8 fragments in registers (one-time, 64 VGPR).
  // B-operand: col = lane&31 (x-row), lane>>5 = k-half (bytes half*32..+31)
  intx8 xf[KSTEPS];
  {
    const float* xr = x + (size_t)(rowBlock + srow) * DIM + half * 32;
#pragma unroll
    for (int ks = 0; ks < KSTEPS; ++ks) {
      int q[8];
#pragma unroll
      for (int j = 0; j < 8; ++j) {
        floatx4 f = *(const floatx4*)(xr + ks * 64 + j * 4);
        q[j] = pk4(f[0], f[1], f[2], f[3]);
      }
      xf[ks] = (intx8){q[0], q[1], q[2], q[3], q[4], q[5], q[6], q[7]};
    }
  }
  __syncthreads();   // csqL/sminU/candCnt init visible

  // per-lane center fragment base pointers (advance once per tile):
  // b0 = centers ctB+0..31 (row l31), b1 = +32 rows (separate base, since
  // 32*512=16384 exceeds the 13-bit signed load immediate)
  const unsigned char* b0p = cq + (size_t)l31 * DIM + half * 32;
  const unsigned char* b1p = b0p + (size_t)32 * DIM;

  intx4 bufA[8], bufB[8];
  LOADP(bufA, b0p, b1p, 0);   // preload pair0 of tile 0

  for (int ct = 0; ct < NCT; ++ct) {
    floatx16 acc0, acc1;      // [center group 0/1] x 32 rows
#pragma unroll
    for (int e = 0; e < 16; ++e) { acc0[e] = 0.f; acc1[e] = 0.f; }

    // software-pipelined K-pairs: issue next pair's loads, compute current.
    LOADP(bufB, b0p, b1p, 2);  COMP(bufA, 0);
    LOADP(bufA, b0p, b1p, 4);  COMP(bufB, 2);
    LOADP(bufB, b0p, b1p, 6);  COMP(bufA, 4);
    b0p += (size_t)TILE_N * DIM;   // advance to next tile (+32768)
    b1p += (size_t)TILE_N * DIM;
    LOADP(bufA, b0p, b1p, 0);  COMP(bufB, 6);   // prefetch next tile's pair0
    // (last tile's wrap prefetch reads csqg-area garbage inside ws: harmless,
    //  never consumed — same precedent as R2/R5 which passed)

    // ---- wave-local epilogue: s(center k) = csq[k] - 2*cross
    // C/D: col = lane&31 (x-row), reg r=4g+e -> center e + 8g + 4*half
    const int ctB = ct << 6;
    float mn = 3.4e38f;
#pragma unroll
    for (int gg = 0; gg < 4; ++gg) {
      floatx4 c0 = *(const floatx4*)&csqL[ctB + 8 * gg + 4 * half];
      floatx4 c1 = *(const floatx4*)&csqL[ctB + 32 + 8 * gg + 4 * half];
#pragma unroll
      for (int e = 0; e < 4; ++e) {
        mn = fminf(mn, c0[e] - 2.f * acc0[4 * gg + e]);
        mn = fminf(mn, c1[e] - 2.f * acc1[4 * gg + e]);
      }
    }
    mn = fminf(mn, __shfl_xor(mn, 32, 64));   // merge the two center-halves
    if (half == 0) atomicMin(&sminU[srow], mapF(mn));
    WAVE_LDS_FENCE();   // intra-wave: atomic retired before threshold read

    const float thr = unmapF(sminU[srow]) + MARGIN;
#pragma unroll
    for (int gg = 0; gg < 4; ++gg) {
      floatx4 c0 = *(const floatx4*)&csqL[ctB + 8 * gg + 4 * half];
      floatx4 c1 = *(const floatx4*)&csqL[ctB + 32 + 8 * gg + 4 * half];
#pragma unroll
      for (int e = 0; e < 4; ++e) {
        float s0 = c0[e] - 2.f * acc0[4 * gg + e];
        if (s0 <= thr) {
          int k = ctB + 8 * gg + 4 * half + e;
          int idx = atomicAdd(&candCnt[wave], 1);
          if (idx < WCAP) { poolK[wave][idx] = ((unsigned)k << 8) | (unsigned)srow; poolS[wave][idx] = s0; }
        }
        float s1 = c1[e] - 2.f * acc1[4 * gg + e];
        if (s1 <= thr) {
          int k = ctB + 32 + 8 * gg + 4 * half + e;
          int idx = atomicAdd(&candCnt[wave], 1);
          if (idx < WCAP) { poolK[wave][idx] = ((unsigned)k << 8) | (unsigned)srow; poolS[wave][idx] = s1; }
        }
      }
    }
    WAVE_LDS_FENCE();

    // wave-local LOSSLESS compaction backstop (wave-uniform branch):
    // lane scans <= WCAP/64 = 16 entries, buffer holds all 16 (R3/R4 lesson:
    // a capped buffer silently drops survivors => wrong argmin).
    if (candCnt[wave] > WTRIG) {
      int cc = candCnt[wave]; if (cc > WCAP) cc = WCAP;
      unsigned myK[16]; float myS[16]; int myN = 0;
      for (int i = lane; i < cc; i += 64) {
        int rl = poolK[wave][i] & 255;
        if (poolS[wave][i] <= unmapF(sminU[rl]) + MARGIN) {
          myK[myN] = poolK[wave][i]; myS[myN] = poolS[wave][i]; ++myN;
        }
      }
      WAVE_LDS_FENCE();                 // survivors in regs before overwrite
      if (lane == 0) candCnt[wave] = 0;
      WAVE_LDS_FENCE();
      int base = atomicAdd(&candCnt[wave], myN);
      for (int j = 0; j < myN; ++j) { poolK[wave][base + j] = myK[j]; poolS[wave][base + j] = myS[j]; }
      WAVE_LDS_FENCE();
    }
  }

  __syncthreads();   // pools/sminU final across waves

  // ---- fp64-exact refinement of surviving candidates (original fp32 inputs)
  const int grp = t >> 4;   // 16 groups of 16 lanes
  const int sl = t & 15;
  for (int w = 0; w < 4; ++w) {
    int cw = candCnt[w]; if (cw > WCAP) cw = WCAP;
    for (int ci = grp; ci < cw; ci += 16) {
      unsigned cd = poolK[w][ci];
      int rl = cd & 255;
      if (poolS[w][ci] > unmapF(sminU[rl]) + MARGIN) continue;  // group-uniform
      int k = cd >> 8;
      const float* xr = x + (size_t)(rowBlock + rl) * DIM;
      const float* cr = cent + (size_t)k * DIM;
      double d = 0.0;
#pragma unroll
      for (int jj = 0; jj < DIM / 64; ++jj) {
        floatx4 xv = *(const floatx4*)(xr + jj * 64 + sl * 4);
        floatx4 cv = *(const floatx4*)(cr + jj * 64 + sl * 4);
#pragma unroll
        for (int e = 0; e < 4; ++e) {
          double df = (double)xv[e] - (double)cv[e];
          d += df * df;
        }
      }
#pragma unroll
      for (int off = 1; off < 16; off <<= 1) d += __shfl_xor(d, off, 64);
      if (sl == 0) {
        // positive doubles order as uint64; low 12 bits -> index (ties: lower k)
        unsigned long long key =
            ((unsigned long long)__double_as_longlong(d) & ~0xFFFull) | (unsigned long long)k;
        atomicMin(&best[rl], key);
      }
    }
  }
  __syncthreads();
  if (t < TILE_M) out[rowBlock + t] = (int)(best[t] & 0xFFFull);
}

// Fallback (no workspace): self-contained 512-thread kernel (known-good).
#define FB_TILE_M 128
#define FB_NKT    32
#define FB_CAP    1536
#define FB_TRIG   1024
__global__ __launch_bounds__(512, 4)
void kmeans_argmin_fb(const float* __restrict__ x, const float* __restrict__ cent,
                      int* __restrict__ out) {
  __shared__ unsigned char ldsA[FB_TILE_M * 64];
  __shared__ unsigned char ldsB[128 * 64];
  __shared__ float csq4[128][4];
  __shared__ unsigned sminU[FB_TILE_M];
  __shared__ unsigned long long best[FB_TILE_M];
  __shared__ unsigned candKey[FB_CAP];
  __shared__ float candS[FB_CAP];
  __shared__ int candCount;

  const int t = threadIdx.x;
  const int lane = t & 63;
  const int wave = t >> 6;
  const int wm = wave >> 1;
  const int wn = wave & 1;
  const int l31 = lane & 31;
  const int half = lane >> 5;
  const int rowBlock = blockIdx.x * FB_TILE_M;

  if (t < FB_TILE_M) { sminU[t] = 0xFFFFFFFFu; best[t] = ~0ull; }
  if (t == 0) candCount = 0;

  const int rS = (t >> 2) & 31;
  const int rowS = (t >> 7) * 32 + rS;
  const int offS = (((t & 3) ^ ((rS >> 1) & 3)) << 4);
  const int qk = half * 2;
  const int fragSlotBase = 4 * l31 + (qk ^ ((l31 >> 1) & 3));

  for (int kt = 0; kt < FB_NKT; ++kt) {
    const int ktBase = kt * 128;
    ((float*)csq4)[t] = 0.f;
    floatx16 acc[2];
#pragma unroll
    for (int fn = 0; fn < 2; ++fn)
#pragma unroll
      for (int e = 0; e < 16; ++e) acc[fn][e] = 0.f;

    for (int ks = 0; ks < KSTEPS; ++ks) {
      const int kd = ks * 64;
      {
        const float* gA = x + (size_t)(rowBlock + rowS) * DIM + kd + offS;
        floatx4 f0 = *(const floatx4*)gA, f1 = *(const floatx4*)(gA + 4);
        floatx4 f2 = *(const floatx4*)(gA + 8), f3 = *(const floatx4*)(gA + 12);
        intx4 q = { pk4(f0[0],f0[1],f0[2],f0[3]), pk4(f1[0],f1[1],f1[2],f1[3]),
                    pk4(f2[0],f2[1],f2[2],f2[3]), pk4(f3[0],f3[1],f3[2],f3[3]) };
        *(intx4*)(ldsA + (size_t)t * 16) = q;
      }
      {
        const float* gB = cent + (size_t)(ktBase + rowS) * DIM + kd + offS;
        floatx4 f0 = *(const floatx4*)gB, f1 = *(const floatx4*)(gB + 4);
        floatx4 f2 = *(const floatx4*)(gB + 8), f3 = *(const floatx4*)(gB + 12);
        intx4 q = { pk4(f0[0],f0[1],f0[2],f0[3]), pk4(f1[0],f1[1],f1[2],f1[3]),
                    pk4(f2[0],f2[1],f2[2],f2[3]), pk4(f3[0],f3[1],f3[2],f3[3]) };
        *(intx4*)(ldsB + (size_t)t * 16) = q;
        float s = 0.f;
#pragma unroll
        for (int e = 0; e < 4; ++e)
          s += f0[e]*f0[e] + f1[e]*f1[e] + f2[e]*f2[e] + f3[e]*f3[e];
        csq4[rowS][t & 3] += s;
      }
      __syncthreads();

      intx8 aF, bF[2];
      {
        int s0 = wm * 128 + fragSlotBase;
        intx4 lo = *(const intx4*)(ldsA + s0 * 16);
        intx4 hi = *(const intx4*)(ldsA + (s0 ^ 1) * 16);
        aF = (intx8){lo[0], lo[1], lo[2], lo[3], hi[0], hi[1], hi[2], hi[3]};
      }
#pragma unroll
      for (int fn = 0; fn < 2; ++fn) {
        int s0 = (wn * 2 + fn) * 128 + fragSlotBase;
        intx4 lo = *(const intx4*)(ldsB + s0 * 16);
        intx4 hi = *(const intx4*)(ldsB + (s0 ^ 1) * 16);
        bF[fn] = (intx8){lo[0], lo[1], lo[2], lo[3], hi[0], hi[1], hi[2], hi[3]};
      }
#pragma unroll
      for (int fn = 0; fn < 2; ++fn)
        acc[fn] = __builtin_amdgcn_mfma_scale_f32_32x32x64_f8f6f4(
            aF, bF[fn], acc[fn], 0, 0, 0, SCALE1, 0, SCALE1);
      __syncthreads();
    }

    float cs[2];
#pragma unroll
    for (int fn = 0; fn < 2; ++fn) {
      int cl = wn * 64 + fn * 32 + l31;
      cs[fn] = csq4[cl][0] + csq4[cl][1] + csq4[cl][2] + csq4[cl][3];
    }

#pragma unroll
    for (int r = 0; r < 16; ++r) {
      float v = fminf(cs[0] - 2.f * acc[0][r], cs[1] - 2.f * acc[1][r]);
      v = fminf(v, __shfl_xor(v, 1, 64));
      v = fminf(v, __shfl_xor(v, 2, 64));
      v = fminf(v, __shfl_xor(v, 4, 64));
      v = fminf(v, __shfl_xor(v, 8, 64));
      v = fminf(v, __shfl_xor(v, 16, 64));
      if (l31 == 0) {
        int srow = wm * 32 + (r & 3) + 8 * (r >> 2) + 4 * half;
        atomicMin(&sminU[srow], mapF(v));
      }
    }
    __syncthreads();

#pragma unroll
    for (int r = 0; r < 16; ++r) {
      int srow = wm * 32 + (r & 3) + 8 * (r >> 2) + 4 * half;
      float thr = unmapF(sminU[srow]) + MARGIN;
#pragma unroll
      for (int fn = 0; fn < 2; ++fn) {
        float s = cs[fn] - 2.f * acc[fn][r];
        if (s <= thr) {
          int k = ktBase + wn * 64 + fn * 32 + l31;
          int idx = atomicAdd(&candCount, 1);
          if (idx < FB_CAP) {
            candKey[idx] = ((unsigned)k << 7) | (unsigned)srow;
            candS[idx] = s;
          }
        }
      }
    }
    __syncthreads();

    if (candCount > FB_TRIG) {
      int cc = candCount; if (cc > FB_CAP) cc = FB_CAP;
      unsigned myK[4]; float myS[4]; int myN = 0;
      for (int i = t; i < cc; i += 512) {
        int rl = candKey[i] & 127;
        if (candS[i] <= unmapF(sminU[rl]) + MARGIN && myN < 4) {
          myK[myN] = candKey[i]; myS[myN] = candS[i]; ++myN;
        }
      }
      __syncthreads();
      if (t == 0) candCount = 0;
      __syncthreads();
      int base = atomicAdd(&candCount, myN);
      for (int j = 0; j < myN; ++j) { candKey[base + j] = myK[j]; candS[base + j] = myS[j]; }
      __syncthreads();
    }
  }

  int cnt = candCount; if (cnt > FB_CAP) cnt = FB_CAP;
  const int g = t >> 4;
  const int sl = t & 15;
  for (int ci = g; ci < cnt; ci += 32) {
    unsigned cd = candKey[ci];
    int rl = cd & 127;
    if (candS[ci] > unmapF(sminU[rl]) + MARGIN) continue;
    int k = cd >> 7;
    const float* xr = x + (size_t)(rowBlock + rl) * DIM;
    const float* cr = cent + (size_t)k * DIM;
    double d = 0.0;
#pragma unroll
    for (int j = 0; j < DIM / 64; ++j) {
      floatx4 xv = *(const floatx4*)(xr + j * 64 + sl * 4);
      floatx4 cv = *(const floatx4*)(cr + j * 64 + sl * 4);
#pragma unroll
      for (int e = 0; e < 4; ++e) {
        double df = (double)xv[e] - (double)cv[e];
        d += df * df;
      }
    }
#pragma unroll
    for (int off = 1; off < 16; off <<= 1) d += __shfl_xor(d, off, 64);
    if (sl == 0) {
      unsigned long long key =
          ((unsigned long long)__double_as_longlong(d) & ~0xFFFull) | (unsigned long long)k;
      atomicMin(&best[rl], key);
    }
  }
  __syncthreads();
  if (t < FB_TILE_M) out[rowBlock + t] = (int)(best[t] & 0xFFFull);
}

extern "C" void kernel_launch(void* const* d_in, const int* in_sizes, int n_in,
                              void* d_out, int out_size, void* d_ws, size_t ws_size,
                              hipStream_t stream) {
  const float* x = (const float*)d_in[0];
  const float* cent = (const float*)d_in[1];
  int* out = (int*)d_out;
  const size_t nXq = (size_t)N_ROWS * DIM;          // ws-size gate (known-good)
  const size_t nCq = (size_t)K_CENT * DIM;          // 2 MiB fp8
  const size_t nCsq = (size_t)K_CENT * sizeof(float);

  if (ws_size >= nXq + nCq + nCsq) {
    unsigned char* cq = (unsigned char*)d_ws;
    float* csqg = (float*)(cq + nCq);
    const size_t total16 = nCq / 16;
    prep_convert<<<(unsigned)((total16 + 255) / 256), 256, 0, stream>>>(cent, cq, csqg);
    kmeans_argmin_pipe<<<N_ROWS / TILE_M, THREADS, 0, stream>>>(x, cent, cq, csqg, out);
  } else {
    kmeans_argmin_fb<<<N_ROWS / FB_TILE_M, 512, 0, stream>>>(x, cent, out);
  }
}